// Round 1
// baseline (315.261 us; speedup 1.0000x reference)
//
#include <hip/hip_runtime.h>
#include <hip/hip_bf16.h>

#define NSLICE 4

using f32x4  = __attribute__((ext_vector_type(4))) float;
using bf16x8 = __attribute__((ext_vector_type(8))) short;

static __device__ inline short f2bs(float f) {
  __hip_bfloat16 h = __float2bfloat16(f);
  return __builtin_bit_cast(short, h);
}

// ---------------- 3-NN over a slice of known points ----------------
__global__ __launch_bounds__(256) void knn_slice_k(
    const float* __restrict__ unknown, const float* __restrict__ known,
    int Ni, int Mi, float* __restrict__ cd, int* __restrict__ ci) {
  int pb = blockIdx.x / NSLICE;
  int sl = blockIdx.x - pb * NSLICE;
  int p  = pb * 256 + threadIdx.x;     // global unknown-point index
  int b  = p / Ni;
  const float* kb = known + (size_t)b * Mi * 3;
  int m0 = (sl * Mi) / NSLICE, m1 = ((sl + 1) * Mi) / NSLICE;

  float ux = unknown[(size_t)p * 3 + 0];
  float uy = unknown[(size_t)p * 3 + 1];
  float uz = unknown[(size_t)p * 3 + 2];

  float b0 = 3e38f, b1 = 3e38f, b2 = 3e38f;
  int   j0 = 0,     j1 = 0,     j2 = 0;
  for (int m = m0; m < m1; ++m) {
    float kx = kb[(size_t)m * 3 + 0];
    float ky = kb[(size_t)m * 3 + 1];
    float kz = kb[(size_t)m * 3 + 2];
    float dx = ux - kx, dy = uy - ky, dz = uz - kz;
    float d = __fmaf_rn(dx, dx, __fmaf_rn(dy, dy, dz * dz));
    if (d < b2) {
      if (d < b1) {
        if (d < b0) { b2 = b1; j2 = j1; b1 = b0; j1 = j0; b0 = d; j0 = m; }
        else        { b2 = b1; j2 = j1; b1 = d;  j1 = m; }
      } else        { b2 = d;  j2 = m; }
    }
  }
  size_t o = ((size_t)p * NSLICE + sl) * 3;
  cd[o + 0] = b0; cd[o + 1] = b1; cd[o + 2] = b2;
  ci[o + 0] = j0; ci[o + 1] = j1; ci[o + 2] = j2;
}

// ---------------- merge per-slice candidates -> weights + idx ----------------
__global__ __launch_bounds__(256) void knn_merge_k(
    const float* __restrict__ cd, const int* __restrict__ ci,
    float* __restrict__ w, int* __restrict__ idx) {
  int p = blockIdx.x * 256 + threadIdx.x;
  float b0 = 3e38f, b1 = 3e38f, b2 = 3e38f;
  int   j0 = 0,     j1 = 0,     j2 = 0;
  size_t base = (size_t)p * NSLICE * 3;
#pragma unroll
  for (int s = 0; s < NSLICE * 3; ++s) {
    float d = cd[base + s];
    int   j = ci[base + s];
    if (d < b2) {
      if (d < b1) {
        if (d < b0) { b2 = b1; j2 = j1; b1 = b0; j1 = j0; b0 = d; j0 = j; }
        else        { b2 = b1; j2 = j1; b1 = d;  j1 = j; }
      } else        { b2 = d;  j2 = j; }
    }
  }
  float d0 = sqrtf(fmaxf(b0, 0.f));
  float d1 = sqrtf(fmaxf(b1, 0.f));
  float d2 = sqrtf(fmaxf(b2, 0.f));
  float r0 = 1.f / (d0 + 1e-8f);
  float r1 = 1.f / (d1 + 1e-8f);
  float r2 = 1.f / (d2 + 1e-8f);
  float rs = 1.f / (r0 + r1 + r2);
  size_t o = (size_t)p * 3;
  w[o] = r0 * rs; w[o + 1] = r1 * rs; w[o + 2] = r2 * rs;
  idx[o] = j0; idx[o + 1] = j1; idx[o + 2] = j2;
}

// ---------------- interpolate + concat -> x0 (bf16, Ntot x 128) ----------------
__global__ __launch_bounds__(256) void interp_k(
    const float* __restrict__ kf, const float* __restrict__ uf,
    const float* __restrict__ w, const int* __restrict__ idx,
    int Ni, int Mi, __hip_bfloat16* __restrict__ x0) {
  int p    = blockIdx.x * 4 + (threadIdx.x >> 6);  // one wave per point
  int lane = threadIdx.x & 63;
  int b = p / Ni;
  const float* kfb = kf + (size_t)b * Mi * 64;
  size_t o = (size_t)p * 3;
  float w0 = w[o], w1 = w[o + 1], w2 = w[o + 2];
  int   i0 = idx[o], i1 = idx[o + 1], i2 = idx[o + 2];
  float v = w0 * kfb[(size_t)i0 * 64 + lane]
          + w1 * kfb[(size_t)i1 * 64 + lane]
          + w2 * kfb[(size_t)i2 * 64 + lane];
  x0[(size_t)p * 128 + lane]      = __float2bfloat16(v);
  x0[(size_t)p * 128 + 64 + lane] = __float2bfloat16(uf[(size_t)p * 64 + lane]);
}

// ---------------- convert weights to bf16 ----------------
__global__ void cvtw_k(const float* __restrict__ W1, const float* __restrict__ W2,
                       __hip_bfloat16* __restrict__ Wb1, __hip_bfloat16* __restrict__ Wb2) {
  int i = blockIdx.x * 256 + threadIdx.x;
  Wb1[i] = __float2bfloat16(W1[i]);
  Wb2[i] = __float2bfloat16(W2[i]);
}

// ---------------- Y = X(bf16, Mx128) @ W^T(bf16 128x128) -> f32 ----------------
__global__ __launch_bounds__(256) void gemm_k(
    const __hip_bfloat16* __restrict__ X, const __hip_bfloat16* __restrict__ Wb,
    float* __restrict__ Y) {
  int wv   = (blockIdx.x * 256 + threadIdx.x) >> 6;  // global wave id, 16 rows each
  int lane = threadIdx.x & 63;
  int row0 = wv * 16;
  int r = lane & 15, g = lane >> 4;
  const short* Xs = reinterpret_cast<const short*>(X);
  const short* Ws = reinterpret_cast<const short*>(Wb);

  bf16x8 a[4];
  size_t abase = (size_t)(row0 + r) * 128 + g * 8;
#pragma unroll
  for (int q = 0; q < 4; ++q)
    a[q] = *reinterpret_cast<const bf16x8*>(Xs + abase + q * 32);

  int rr = row0 + g * 4;
#pragma unroll
  for (int ct = 0; ct < 8; ++ct) {
    f32x4 acc = {0.f, 0.f, 0.f, 0.f};
    size_t bbase = (size_t)(ct * 16 + r) * 128 + g * 8;
#pragma unroll
    for (int q = 0; q < 4; ++q) {
      bf16x8 bfr = *reinterpret_cast<const bf16x8*>(Ws + bbase + q * 32);
      acc = __builtin_amdgcn_mfma_f32_16x16x32_bf16(a[q], bfr, acc, 0, 0, 0);
    }
    int c = ct * 16 + r;
#pragma unroll
    for (int i = 0; i < 4; ++i)
      Y[(size_t)(rr + i) * 128 + c] = acc[i];
  }
}

// ---------------- per-column sum / sumsq over all rows ----------------
__global__ __launch_bounds__(256) void colstats_k(
    const float* __restrict__ Y, long n4, float* __restrict__ stats) {
  __shared__ float ls[128], lq[128];
  if (threadIdx.x < 128) { ls[threadIdx.x] = 0.f; lq[threadIdx.x] = 0.f; }
  __syncthreads();
  float s[4] = {0, 0, 0, 0}, q[4] = {0, 0, 0, 0};
  long i = (long)blockIdx.x * 256 + threadIdx.x;
  long stride = (long)gridDim.x * 256;
  int c0 = (int)((i * 4) & 127);  // stride*4 % 128 == 0 -> constant per thread
  for (; i < n4; i += stride) {
    f32x4 y = reinterpret_cast<const f32x4*>(Y)[i];
#pragma unroll
    for (int j = 0; j < 4; ++j) { s[j] += y[j]; q[j] += y[j] * y[j]; }
  }
#pragma unroll
  for (int j = 0; j < 4; ++j) {
    atomicAdd(&ls[c0 + j], s[j]);
    atomicAdd(&lq[c0 + j], q[j]);
  }
  __syncthreads();
  if (threadIdx.x < 128) {
    atomicAdd(&stats[threadIdx.x], ls[threadIdx.x]);
    atomicAdd(&stats[128 + threadIdx.x], lq[threadIdx.x]);
  }
}

// ---------------- stats -> affine coeffs A,B per column ----------------
__global__ void finalize_k(const float* __restrict__ stats, const float* __restrict__ g,
                           const float* __restrict__ bb, float invN, float* __restrict__ AB) {
  int c = threadIdx.x;
  float mu  = stats[c] * invN;
  float var = stats[128 + c] * invN - mu * mu;
  float A = rsqrtf(var + 1e-5f) * g[c];
  AB[c] = A;
  AB[128 + c] = bb[c] - mu * A;
}

// ---------------- BN+ReLU -> bf16 (for next GEMM input) ----------------
__global__ __launch_bounds__(256) void bnrelu_bf16_k(
    const float* __restrict__ Y, const float* __restrict__ AB,
    __hip_bfloat16* __restrict__ Xo, long n4) {
  long i = (long)blockIdx.x * 256 + threadIdx.x;
  long stride = (long)gridDim.x * 256;
  for (; i < n4; i += stride) {
    f32x4 y = reinterpret_cast<const f32x4*>(Y)[i];
    int c0 = (int)((i * 4) & 127);
    f32x4 A  = *reinterpret_cast<const f32x4*>(AB + c0);
    f32x4 Bv = *reinterpret_cast<const f32x4*>(AB + 128 + c0);
    short4 o;
    o.x = f2bs(fmaxf(y[0] * A[0] + Bv[0], 0.f));
    o.y = f2bs(fmaxf(y[1] * A[1] + Bv[1], 0.f));
    o.z = f2bs(fmaxf(y[2] * A[2] + Bv[2], 0.f));
    o.w = f2bs(fmaxf(y[3] * A[3] + Bv[3], 0.f));
    *reinterpret_cast<short4*>(reinterpret_cast<short*>(Xo) + i * 4) = o;
  }
}

// ---------------- BN+ReLU in-place f32 (final output) ----------------
__global__ __launch_bounds__(256) void bnrelu_f32_k(
    float* __restrict__ Y, const float* __restrict__ AB, long n4) {
  long i = (long)blockIdx.x * 256 + threadIdx.x;
  long stride = (long)gridDim.x * 256;
  for (; i < n4; i += stride) {
    f32x4 y = reinterpret_cast<f32x4*>(Y)[i];
    int c0 = (int)((i * 4) & 127);
    f32x4 A  = *reinterpret_cast<const f32x4*>(AB + c0);
    f32x4 Bv = *reinterpret_cast<const f32x4*>(AB + 128 + c0);
    f32x4 o;
#pragma unroll
    for (int j = 0; j < 4; ++j) o[j] = fmaxf(y[j] * A[j] + Bv[j], 0.f);
    reinterpret_cast<f32x4*>(Y)[i] = o;
  }
}

extern "C" void kernel_launch(void* const* d_in, const int* in_sizes, int n_in,
                              void* d_out, int out_size, void* d_ws, size_t ws_size,
                              hipStream_t stream) {
  const float* unknown = (const float*)d_in[0];
  const float* known   = (const float*)d_in[2];
  const float* uf      = (const float*)d_in[4];
  const float* kf      = (const float*)d_in[5];
  const float* W1      = (const float*)d_in[6];
  const float* g1      = (const float*)d_in[7];
  const float* b1      = (const float*)d_in[8];
  const float* W2      = (const float*)d_in[9];
  const float* g2      = (const float*)d_in[10];
  const float* b2      = (const float*)d_in[11];

  int B    = in_sizes[1];
  int Ntot = in_sizes[0] / 3;
  int Mtot = in_sizes[2] / 3;
  int Ni = Ntot / B, Mi = Mtot / B;

  char* ws = (char*)d_ws;
  size_t off = 0;
  auto alloc = [&](size_t bytes) {
    void* p = ws + off;
    off += (bytes + 255) & ~(size_t)255;
    return p;
  };
  float* cd  = (float*)alloc((size_t)Ntot * NSLICE * 3 * 4);
  int*   ci  = (int*)  alloc((size_t)Ntot * NSLICE * 3 * 4);
  float* wgt = (float*)alloc((size_t)Ntot * 3 * 4);
  int*   idx = (int*)  alloc((size_t)Ntot * 3 * 4);
  __hip_bfloat16* x0 = (__hip_bfloat16*)alloc((size_t)Ntot * 128 * 2);
  float* y1 = (float*)alloc((size_t)Ntot * 128 * 4);
  __hip_bfloat16* x1 = (__hip_bfloat16*)alloc((size_t)Ntot * 128 * 2);
  __hip_bfloat16* Wb1 = (__hip_bfloat16*)alloc(128 * 128 * 2);
  __hip_bfloat16* Wb2 = (__hip_bfloat16*)alloc(128 * 128 * 2);
  float* stats = (float*)alloc(2 * 256 * 4);  // [stats1(256) | stats2(256)]
  float* AB1 = (float*)alloc(256 * 4);
  float* AB2 = (float*)alloc(256 * 4);

  float* y2 = (float*)d_out;
  long n4 = (long)Ntot * 128 / 4;
  float invN = 1.0f / (float)Ntot;

  hipMemsetAsync(stats, 0, 2 * 256 * 4, stream);
  cvtw_k<<<64, 256, 0, stream>>>(W1, W2, Wb1, Wb2);
  knn_slice_k<<<(Ntot / 256) * NSLICE, 256, 0, stream>>>(unknown, known, Ni, Mi, cd, ci);
  knn_merge_k<<<Ntot / 256, 256, 0, stream>>>(cd, ci, wgt, idx);
  interp_k<<<Ntot / 4, 256, 0, stream>>>(kf, uf, wgt, idx, Ni, Mi, x0);
  gemm_k<<<Ntot / 64, 256, 0, stream>>>(x0, Wb1, y1);
  colstats_k<<<1024, 256, 0, stream>>>(y1, n4, stats);
  finalize_k<<<1, 128, 0, stream>>>(stats, g1, b1, invN, AB1);
  bnrelu_bf16_k<<<2048, 256, 0, stream>>>(y1, AB1, x1, n4);
  gemm_k<<<Ntot / 64, 256, 0, stream>>>(x1, Wb2, y2);
  colstats_k<<<1024, 256, 0, stream>>>(y2, n4, stats + 256);
  finalize_k<<<1, 128, 0, stream>>>(stats + 256, g2, b2, invN, AB2);
  bnrelu_f32_k<<<2048, 256, 0, stream>>>(y2, AB2, n4);
}

// Round 2
// 280.247 us; speedup vs baseline: 1.1249x; 1.1249x over previous
//
#include <hip/hip_runtime.h>
#include <hip/hip_bf16.h>

#define NSLICE 4

using f32x4  = __attribute__((ext_vector_type(4))) float;
using bf16x8 = __attribute__((ext_vector_type(8))) short;

static __device__ inline short f2bs(float f) {
  __hip_bfloat16 h = __float2bfloat16(f);
  return __builtin_bit_cast(short, h);
}

// ---------------- pack known points into float4 for scalar-load loop ----------------
__global__ __launch_bounds__(256) void pack_known_k(
    const float* __restrict__ known, int Mtot, f32x4* __restrict__ k4) {
  int m = blockIdx.x * 256 + threadIdx.x;
  if (m < Mtot) {
    float x = known[(size_t)m * 3 + 0];
    float y = known[(size_t)m * 3 + 1];
    float z = known[(size_t)m * 3 + 2];
    f32x4 v; v[0] = x; v[1] = y; v[2] = z; v[3] = 0.f;
    k4[m] = v;
  }
}

// ---------------- 3-NN over a slice of known points (scalar k-loads) ----------------
__global__ __launch_bounds__(256) void knn_slice_k(
    const float* __restrict__ unknown, const f32x4* __restrict__ k4,
    int Ni, int Mi, float* __restrict__ cd, int* __restrict__ ci) {
  int pb = blockIdx.x / NSLICE;
  int sl = blockIdx.x - pb * NSLICE;
  int p  = pb * 256 + threadIdx.x;        // global unknown-point index
  int b  = (pb * 256) / Ni;               // block-uniform (Ni % 256 == 0) -> SGPR base
  const f32x4* kb = k4 + (size_t)b * Mi;
  int cnt = Mi / NSLICE;
  int m0  = sl * cnt;

  float ux = unknown[(size_t)p * 3 + 0];
  float uy = unknown[(size_t)p * 3 + 1];
  float uz = unknown[(size_t)p * 3 + 2];

  float b0 = 3e38f, b1 = 3e38f, b2 = 3e38f;
  int   j0 = 0,     j1 = 0,     j2 = 0;
#pragma unroll 4
  for (int t = 0; t < cnt; ++t) {
    f32x4 k = kb[m0 + t];                 // uniform address -> s_load_dwordx4
    float dx = ux - k[0], dy = uy - k[1], dz = uz - k[2];
    float d = __fmaf_rn(dx, dx, __fmaf_rn(dy, dy, dz * dz));
    if (d < b2) {
      int m = m0 + t;
      if (d < b1) {
        if (d < b0) { b2 = b1; j2 = j1; b1 = b0; j1 = j0; b0 = d; j0 = m; }
        else        { b2 = b1; j2 = j1; b1 = d;  j1 = m; }
      } else        { b2 = d;  j2 = m; }
    }
  }
  size_t o = ((size_t)p * NSLICE + sl) * 3;
  cd[o + 0] = b0; cd[o + 1] = b1; cd[o + 2] = b2;
  ci[o + 0] = j0; ci[o + 1] = j1; ci[o + 2] = j2;
}

// ---------------- merge per-slice candidates -> weights + idx ----------------
__global__ __launch_bounds__(256) void knn_merge_k(
    const float* __restrict__ cd, const int* __restrict__ ci,
    float* __restrict__ w, int* __restrict__ idx) {
  int p = blockIdx.x * 256 + threadIdx.x;
  float b0 = 3e38f, b1 = 3e38f, b2 = 3e38f;
  int   j0 = 0,     j1 = 0,     j2 = 0;
  size_t base = (size_t)p * NSLICE * 3;
#pragma unroll
  for (int s = 0; s < NSLICE * 3; ++s) {
    float d = cd[base + s];
    int   j = ci[base + s];
    if (d < b2) {
      if (d < b1) {
        if (d < b0) { b2 = b1; j2 = j1; b1 = b0; j1 = j0; b0 = d; j0 = j; }
        else        { b2 = b1; j2 = j1; b1 = d;  j1 = j; }
      } else        { b2 = d;  j2 = j; }
    }
  }
  float d0 = sqrtf(fmaxf(b0, 0.f));
  float d1 = sqrtf(fmaxf(b1, 0.f));
  float d2 = sqrtf(fmaxf(b2, 0.f));
  float r0 = 1.f / (d0 + 1e-8f);
  float r1 = 1.f / (d1 + 1e-8f);
  float r2 = 1.f / (d2 + 1e-8f);
  float rs = 1.f / (r0 + r1 + r2);
  size_t o = (size_t)p * 3;
  w[o] = r0 * rs; w[o + 1] = r1 * rs; w[o + 2] = r2 * rs;
  idx[o] = j0; idx[o + 1] = j1; idx[o + 2] = j2;
}

// ---------------- interpolate + concat -> x0 (bf16, Ntot x 128) ----------------
__global__ __launch_bounds__(256) void interp_k(
    const float* __restrict__ kf, const float* __restrict__ uf,
    const float* __restrict__ w, const int* __restrict__ idx,
    int Ni, int Mi, __hip_bfloat16* __restrict__ x0) {
  int p    = blockIdx.x * 4 + (threadIdx.x >> 6);  // one wave per point
  int lane = threadIdx.x & 63;
  int b = p / Ni;
  const float* kfb = kf + (size_t)b * Mi * 64;
  size_t o = (size_t)p * 3;
  float w0 = w[o], w1 = w[o + 1], w2 = w[o + 2];
  int   i0 = idx[o], i1 = idx[o + 1], i2 = idx[o + 2];
  float v = w0 * kfb[(size_t)i0 * 64 + lane]
          + w1 * kfb[(size_t)i1 * 64 + lane]
          + w2 * kfb[(size_t)i2 * 64 + lane];
  x0[(size_t)p * 128 + lane]      = __float2bfloat16(v);
  x0[(size_t)p * 128 + 64 + lane] = __float2bfloat16(uf[(size_t)p * 64 + lane]);
}

// ---------------- convert weights to bf16 ----------------
__global__ void cvtw_k(const float* __restrict__ W1, const float* __restrict__ W2,
                       __hip_bfloat16* __restrict__ Wb1, __hip_bfloat16* __restrict__ Wb2) {
  int i = blockIdx.x * 256 + threadIdx.x;
  Wb1[i] = __float2bfloat16(W1[i]);
  Wb2[i] = __float2bfloat16(W2[i]);
}

// ---------------- Y = X(bf16, Mx128) @ W^T(bf16 128x128) -> f32 ----------------
__global__ __launch_bounds__(256) void gemm_k(
    const __hip_bfloat16* __restrict__ X, const __hip_bfloat16* __restrict__ Wb,
    float* __restrict__ Y) {
  int wv   = (blockIdx.x * 256 + threadIdx.x) >> 6;  // global wave id, 16 rows each
  int lane = threadIdx.x & 63;
  int row0 = wv * 16;
  int r = lane & 15, g = lane >> 4;
  const short* Xs = reinterpret_cast<const short*>(X);
  const short* Ws = reinterpret_cast<const short*>(Wb);

  bf16x8 a[4];
  size_t abase = (size_t)(row0 + r) * 128 + g * 8;
#pragma unroll
  for (int q = 0; q < 4; ++q)
    a[q] = *reinterpret_cast<const bf16x8*>(Xs + abase + q * 32);

  int rr = row0 + g * 4;
#pragma unroll
  for (int ct = 0; ct < 8; ++ct) {
    f32x4 acc = {0.f, 0.f, 0.f, 0.f};
    size_t bbase = (size_t)(ct * 16 + r) * 128 + g * 8;
#pragma unroll
    for (int q = 0; q < 4; ++q) {
      bf16x8 bfr = *reinterpret_cast<const bf16x8*>(Ws + bbase + q * 32);
      acc = __builtin_amdgcn_mfma_f32_16x16x32_bf16(a[q], bfr, acc, 0, 0, 0);
    }
    int c = ct * 16 + r;
#pragma unroll
    for (int i = 0; i < 4; ++i)
      Y[(size_t)(rr + i) * 128 + c] = acc[i];
  }
}

// ---------------- per-column sum / sumsq over all rows ----------------
__global__ __launch_bounds__(256) void colstats_k(
    const float* __restrict__ Y, long n4, float* __restrict__ stats) {
  __shared__ float ls[128], lq[128];
  if (threadIdx.x < 128) { ls[threadIdx.x] = 0.f; lq[threadIdx.x] = 0.f; }
  __syncthreads();
  float s[4] = {0, 0, 0, 0}, q[4] = {0, 0, 0, 0};
  long i = (long)blockIdx.x * 256 + threadIdx.x;
  long stride = (long)gridDim.x * 256;
  int c0 = (int)((i * 4) & 127);  // stride*4 % 128 == 0 -> constant per thread
  for (; i < n4; i += stride) {
    f32x4 y = reinterpret_cast<const f32x4*>(Y)[i];
#pragma unroll
    for (int j = 0; j < 4; ++j) { s[j] += y[j]; q[j] += y[j] * y[j]; }
  }
#pragma unroll
  for (int j = 0; j < 4; ++j) {
    atomicAdd(&ls[c0 + j], s[j]);
    atomicAdd(&lq[c0 + j], q[j]);
  }
  __syncthreads();
  if (threadIdx.x < 128) {
    atomicAdd(&stats[threadIdx.x], ls[threadIdx.x]);
    atomicAdd(&stats[128 + threadIdx.x], lq[threadIdx.x]);
  }
}

// ---------------- stats -> affine coeffs A,B per column ----------------
__global__ void finalize_k(const float* __restrict__ stats, const float* __restrict__ g,
                           const float* __restrict__ bb, float invN, float* __restrict__ AB) {
  int c = threadIdx.x;
  float mu  = stats[c] * invN;
  float var = stats[128 + c] * invN - mu * mu;
  float A = rsqrtf(var + 1e-5f) * g[c];
  AB[c] = A;
  AB[128 + c] = bb[c] - mu * A;
}

// ---------------- BN+ReLU -> bf16 (for next GEMM input) ----------------
__global__ __launch_bounds__(256) void bnrelu_bf16_k(
    const float* __restrict__ Y, const float* __restrict__ AB,
    __hip_bfloat16* __restrict__ Xo, long n4) {
  long i = (long)blockIdx.x * 256 + threadIdx.x;
  long stride = (long)gridDim.x * 256;
  for (; i < n4; i += stride) {
    f32x4 y = reinterpret_cast<const f32x4*>(Y)[i];
    int c0 = (int)((i * 4) & 127);
    f32x4 A  = *reinterpret_cast<const f32x4*>(AB + c0);
    f32x4 Bv = *reinterpret_cast<const f32x4*>(AB + 128 + c0);
    short4 o;
    o.x = f2bs(fmaxf(y[0] * A[0] + Bv[0], 0.f));
    o.y = f2bs(fmaxf(y[1] * A[1] + Bv[1], 0.f));
    o.z = f2bs(fmaxf(y[2] * A[2] + Bv[2], 0.f));
    o.w = f2bs(fmaxf(y[3] * A[3] + Bv[3], 0.f));
    *reinterpret_cast<short4*>(reinterpret_cast<short*>(Xo) + i * 4) = o;
  }
}

// ---------------- BN+ReLU in-place f32 (final output) ----------------
__global__ __launch_bounds__(256) void bnrelu_f32_k(
    float* __restrict__ Y, const float* __restrict__ AB, long n4) {
  long i = (long)blockIdx.x * 256 + threadIdx.x;
  long stride = (long)gridDim.x * 256;
  for (; i < n4; i += stride) {
    f32x4 y = reinterpret_cast<f32x4*>(Y)[i];
    int c0 = (int)((i * 4) & 127);
    f32x4 A  = *reinterpret_cast<const f32x4*>(AB + c0);
    f32x4 Bv = *reinterpret_cast<const f32x4*>(AB + 128 + c0);
    f32x4 o;
#pragma unroll
    for (int j = 0; j < 4; ++j) o[j] = fmaxf(y[j] * A[j] + Bv[j], 0.f);
    reinterpret_cast<f32x4*>(Y)[i] = o;
  }
}

extern "C" void kernel_launch(void* const* d_in, const int* in_sizes, int n_in,
                              void* d_out, int out_size, void* d_ws, size_t ws_size,
                              hipStream_t stream) {
  const float* unknown = (const float*)d_in[0];
  const float* known   = (const float*)d_in[2];
  const float* uf      = (const float*)d_in[4];
  const float* kf      = (const float*)d_in[5];
  const float* W1      = (const float*)d_in[6];
  const float* g1      = (const float*)d_in[7];
  const float* b1      = (const float*)d_in[8];
  const float* W2      = (const float*)d_in[9];
  const float* g2      = (const float*)d_in[10];
  const float* b2      = (const float*)d_in[11];

  int B    = in_sizes[1];
  int Ntot = in_sizes[0] / 3;
  int Mtot = in_sizes[2] / 3;
  int Ni = Ntot / B, Mi = Mtot / B;

  char* ws = (char*)d_ws;
  size_t off = 0;
  auto alloc = [&](size_t bytes) {
    void* p = ws + off;
    off += (bytes + 255) & ~(size_t)255;
    return p;
  };
  f32x4* k4  = (f32x4*)alloc((size_t)Mtot * 16);
  float* cd  = (float*)alloc((size_t)Ntot * NSLICE * 3 * 4);
  int*   ci  = (int*)  alloc((size_t)Ntot * NSLICE * 3 * 4);
  float* wgt = (float*)alloc((size_t)Ntot * 3 * 4);
  int*   idx = (int*)  alloc((size_t)Ntot * 3 * 4);
  __hip_bfloat16* x0 = (__hip_bfloat16*)alloc((size_t)Ntot * 128 * 2);
  float* y1 = (float*)alloc((size_t)Ntot * 128 * 4);
  __hip_bfloat16* x1 = (__hip_bfloat16*)alloc((size_t)Ntot * 128 * 2);
  __hip_bfloat16* Wb1 = (__hip_bfloat16*)alloc(128 * 128 * 2);
  __hip_bfloat16* Wb2 = (__hip_bfloat16*)alloc(128 * 128 * 2);
  float* stats = (float*)alloc(2 * 256 * 4);  // [stats1(256) | stats2(256)]
  float* AB1 = (float*)alloc(256 * 4);
  float* AB2 = (float*)alloc(256 * 4);

  float* y2 = (float*)d_out;
  long n4 = (long)Ntot * 128 / 4;
  float invN = 1.0f / (float)Ntot;

  hipMemsetAsync(stats, 0, 2 * 256 * 4, stream);
  cvtw_k<<<64, 256, 0, stream>>>(W1, W2, Wb1, Wb2);
  pack_known_k<<<(Mtot + 255) / 256, 256, 0, stream>>>(known, Mtot, k4);
  knn_slice_k<<<(Ntot / 256) * NSLICE, 256, 0, stream>>>(unknown, k4, Ni, Mi, cd, ci);
  knn_merge_k<<<Ntot / 256, 256, 0, stream>>>(cd, ci, wgt, idx);
  interp_k<<<Ntot / 4, 256, 0, stream>>>(kf, uf, wgt, idx, Ni, Mi, x0);
  gemm_k<<<Ntot / 64, 256, 0, stream>>>(x0, Wb1, y1);
  colstats_k<<<1024, 256, 0, stream>>>(y1, n4, stats);
  finalize_k<<<1, 128, 0, stream>>>(stats, g1, b1, invN, AB1);
  bnrelu_bf16_k<<<2048, 256, 0, stream>>>(y1, AB1, x1, n4);
  gemm_k<<<Ntot / 64, 256, 0, stream>>>(x1, Wb2, y2);
  colstats_k<<<1024, 256, 0, stream>>>(y2, n4, stats + 256);
  finalize_k<<<1, 128, 0, stream>>>(stats + 256, g2, b2, invN, AB2);
  bnrelu_f32_k<<<2048, 256, 0, stream>>>(y2, AB2, n4);
}

// Round 3
// 232.520 us; speedup vs baseline: 1.3558x; 1.2053x over previous
//
#include <hip/hip_runtime.h>
#include <hip/hip_bf16.h>

#define NSLICE 8

using f32x4  = __attribute__((ext_vector_type(4))) float;
using f32x16 = __attribute__((ext_vector_type(16))) float;
using bf16x8 = __attribute__((ext_vector_type(8))) short;

static __device__ inline short f2bs(float f) {
  __hip_bfloat16 h = __float2bfloat16(f);
  return __builtin_bit_cast(short, h);
}
static __device__ inline float bs2f(short s) {
  return __bfloat162float(__builtin_bit_cast(__hip_bfloat16, s));
}

// ---- pack known points as (-2x, -2y, -2z, |k|^2) for the expansion form ----
__global__ __launch_bounds__(256) void pack_known_k(
    const float* __restrict__ known, int Mtot, f32x4* __restrict__ k4) {
  int m = blockIdx.x * 256 + threadIdx.x;
  if (m < Mtot) {
    float x = known[(size_t)m * 3 + 0];
    float y = known[(size_t)m * 3 + 1];
    float z = known[(size_t)m * 3 + 2];
    f32x4 v;
    v[0] = -2.f * x; v[1] = -2.f * y; v[2] = -2.f * z;
    v[3] = x * x + y * y + z * z;
    k4[m] = v;
  }
}

#define INS(dv, mv)                                                          \
  if (dv < b2) {                                                             \
    if (dv < b1) {                                                           \
      if (dv < b0) { b2 = b1; j2 = j1; b1 = b0; j1 = j0; b0 = dv; j0 = mv; } \
      else         { b2 = b1; j2 = j1; b1 = dv; j1 = mv; }                   \
    } else         { b2 = dv; j2 = mv; }                                     \
  }

// ---- 3-NN over a slice: d' = |k|^2 - 2 u.k  (monotone in true d^2) ----
__global__ __launch_bounds__(256) void knn_slice_k(
    const float* __restrict__ unknown, const f32x4* __restrict__ k4,
    int Ni, int Mi, float* __restrict__ cd, int* __restrict__ ci) {
  int pb = blockIdx.x / NSLICE;
  int sl = blockIdx.x - pb * NSLICE;
  int p  = pb * 256 + threadIdx.x;
  int b  = (pb * 256) / Ni;               // block-uniform (Ni % 256 == 0)
  const f32x16* kb16 = reinterpret_cast<const f32x16*>(k4 + (size_t)b * Mi);
  int cnt = Mi / NSLICE;                  // 512, divisible by 4
  int m0  = sl * cnt;

  float ux = unknown[(size_t)p * 3 + 0];
  float uy = unknown[(size_t)p * 3 + 1];
  float uz = unknown[(size_t)p * 3 + 2];

  float b0 = 3e38f, b1 = 3e38f, b2 = 3e38f;
  int   j0 = 0,     j1 = 0,     j2 = 0;
#pragma unroll 2
  for (int t = 0; t < cnt; t += 4) {
    f32x16 kc = kb16[(m0 + t) >> 2];      // uniform -> s_load_dwordx16
    float d0 = __fmaf_rn(ux, kc[0],  __fmaf_rn(uy, kc[1],  __fmaf_rn(uz, kc[2],  kc[3])));
    float d1 = __fmaf_rn(ux, kc[4],  __fmaf_rn(uy, kc[5],  __fmaf_rn(uz, kc[6],  kc[7])));
    float d2 = __fmaf_rn(ux, kc[8],  __fmaf_rn(uy, kc[9],  __fmaf_rn(uz, kc[10], kc[11])));
    float d3 = __fmaf_rn(ux, kc[12], __fmaf_rn(uy, kc[13], __fmaf_rn(uz, kc[14], kc[15])));
    float mn = fminf(fminf(d0, d1), fminf(d2, d3));
    if (mn < b2) {
      INS(d0, m0 + t + 0);
      INS(d1, m0 + t + 1);
      INS(d2, m0 + t + 2);
      INS(d3, m0 + t + 3);
    }
  }
  size_t o = ((size_t)p * NSLICE + sl) * 3;
  cd[o + 0] = b0; cd[o + 1] = b1; cd[o + 2] = b2;
  ci[o + 0] = j0; ci[o + 1] = j1; ci[o + 2] = j2;
}

// ---- merge per-slice candidates -> weights + idx ----
__global__ __launch_bounds__(256) void knn_merge_k(
    const float* __restrict__ unknown,
    const float* __restrict__ cd, const int* __restrict__ ci,
    float* __restrict__ w, int* __restrict__ idx) {
  int p = blockIdx.x * 256 + threadIdx.x;
  float b0 = 3e38f, b1 = 3e38f, b2 = 3e38f;
  int   j0 = 0,     j1 = 0,     j2 = 0;
  size_t base = (size_t)p * NSLICE * 3;
#pragma unroll
  for (int s = 0; s < NSLICE * 3; ++s) {
    float dv = cd[base + s];
    int   jv = ci[base + s];
    INS(dv, jv);
  }
  float ux = unknown[(size_t)p * 3 + 0];
  float uy = unknown[(size_t)p * 3 + 1];
  float uz = unknown[(size_t)p * 3 + 2];
  float uu = ux * ux + uy * uy + uz * uz;
  float d0 = sqrtf(fmaxf(b0 + uu, 0.f));
  float d1 = sqrtf(fmaxf(b1 + uu, 0.f));
  float d2 = sqrtf(fmaxf(b2 + uu, 0.f));
  float r0 = 1.f / (d0 + 1e-8f);
  float r1 = 1.f / (d1 + 1e-8f);
  float r2 = 1.f / (d2 + 1e-8f);
  float rs = 1.f / (r0 + r1 + r2);
  size_t o = (size_t)p * 3;
  w[o] = r0 * rs; w[o + 1] = r1 * rs; w[o + 2] = r2 * rs;
  idx[o] = j0; idx[o + 1] = j1; idx[o + 2] = j2;
}

// ---- interpolate + concat -> x0 (bf16, Ntot x 128) ----
__global__ __launch_bounds__(256) void interp_k(
    const float* __restrict__ kf, const float* __restrict__ uf,
    const float* __restrict__ w, const int* __restrict__ idx,
    int Ni, int Mi, __hip_bfloat16* __restrict__ x0) {
  int p    = blockIdx.x * 4 + (threadIdx.x >> 6);  // one wave per point
  int lane = threadIdx.x & 63;
  int b = p / Ni;
  const float* kfb = kf + (size_t)b * Mi * 64;
  size_t o = (size_t)p * 3;
  float w0 = w[o], w1 = w[o + 1], w2 = w[o + 2];
  int   i0 = idx[o], i1 = idx[o + 1], i2 = idx[o + 2];
  float v = w0 * kfb[(size_t)i0 * 64 + lane]
          + w1 * kfb[(size_t)i1 * 64 + lane]
          + w2 * kfb[(size_t)i2 * 64 + lane];
  x0[(size_t)p * 128 + lane]      = __float2bfloat16(v);
  x0[(size_t)p * 128 + 64 + lane] = __float2bfloat16(uf[(size_t)p * 64 + lane]);
}

// ---- convert weights to bf16 ----
__global__ void cvtw_k(const float* __restrict__ W1, const float* __restrict__ W2,
                       __hip_bfloat16* __restrict__ Wb1, __hip_bfloat16* __restrict__ Wb2) {
  int i = blockIdx.x * 256 + threadIdx.x;
  Wb1[i] = __float2bfloat16(W1[i]);
  Wb2[i] = __float2bfloat16(W2[i]);
}

// ---- Y = X(bf16 Mx128) @ W^T(bf16 128x128), fused column-stats epilogue ----
// Writes Yf (f32) if non-null, else Yb (bf16). stats += per-column {sum, sumsq}.
__global__ __launch_bounds__(256) void gemm_stats_k(
    const __hip_bfloat16* __restrict__ X, const __hip_bfloat16* __restrict__ Wb,
    float* __restrict__ Yf, __hip_bfloat16* __restrict__ Yb,
    float* __restrict__ stats) {
  __shared__ float ls[128], lq[128];
  if (threadIdx.x < 128) { ls[threadIdx.x] = 0.f; lq[threadIdx.x] = 0.f; }
  __syncthreads();

  int wv   = (blockIdx.x * 256 + threadIdx.x) >> 6;
  int lane = threadIdx.x & 63;
  int row0 = wv * 16;
  int r = lane & 15, g = lane >> 4;
  const short* Xs = reinterpret_cast<const short*>(X);
  const short* Ws = reinterpret_cast<const short*>(Wb);

  bf16x8 a[4];
  size_t abase = (size_t)(row0 + r) * 128 + g * 8;
#pragma unroll
  for (int q = 0; q < 4; ++q)
    a[q] = *reinterpret_cast<const bf16x8*>(Xs + abase + q * 32);

  int rr = row0 + g * 4;
#pragma unroll
  for (int ct = 0; ct < 8; ++ct) {
    f32x4 acc = {0.f, 0.f, 0.f, 0.f};
    size_t bbase = (size_t)(ct * 16 + r) * 128 + g * 8;
#pragma unroll
    for (int q = 0; q < 4; ++q) {
      bf16x8 bfr = *reinterpret_cast<const bf16x8*>(Ws + bbase + q * 32);
      acc = __builtin_amdgcn_mfma_f32_16x16x32_bf16(a[q], bfr, acc, 0, 0, 0);
    }
    int c = ct * 16 + r;
    if (Yf) {
#pragma unroll
      for (int i = 0; i < 4; ++i)
        Yf[(size_t)(rr + i) * 128 + c] = acc[i];
    } else {
#pragma unroll
      for (int i = 0; i < 4; ++i)
        Yb[(size_t)(rr + i) * 128 + c] = __float2bfloat16(acc[i]);
    }
    float s = acc[0] + acc[1] + acc[2] + acc[3];
    float q2 = acc[0] * acc[0] + acc[1] * acc[1] + acc[2] * acc[2] + acc[3] * acc[3];
    s  += __shfl_xor(s, 16);  s  += __shfl_xor(s, 32);
    q2 += __shfl_xor(q2, 16); q2 += __shfl_xor(q2, 32);
    if (g == 0) {
      atomicAdd(&ls[c], s);
      atomicAdd(&lq[c], q2);
    }
  }
  __syncthreads();
  if (threadIdx.x < 128) {
    atomicAdd(&stats[threadIdx.x], ls[threadIdx.x]);
    atomicAdd(&stats[128 + threadIdx.x], lq[threadIdx.x]);
  }
}

// ---- stats -> affine coeffs A,B per column ----
__global__ void finalize_k(const float* __restrict__ stats, const float* __restrict__ g,
                           const float* __restrict__ bb, float invN, float* __restrict__ AB) {
  int c = threadIdx.x;
  float mu  = stats[c] * invN;
  float var = stats[128 + c] * invN - mu * mu;
  float A = rsqrtf(var + 1e-5f) * g[c];
  AB[c] = A;
  AB[128 + c] = bb[c] - mu * A;
}

// ---- BN+ReLU on bf16 input -> bf16 output (next GEMM input) ----
__global__ __launch_bounds__(256) void bnrelu_bf16_k(
    const __hip_bfloat16* __restrict__ Y, const float* __restrict__ AB,
    __hip_bfloat16* __restrict__ Xo, long n8) {
  long i = (long)blockIdx.x * 256 + threadIdx.x;
  long stride = (long)gridDim.x * 256;
  const bf16x8* Y8 = reinterpret_cast<const bf16x8*>(Y);
  bf16x8* X8 = reinterpret_cast<bf16x8*>(Xo);
  for (; i < n8; i += stride) {
    bf16x8 y = Y8[i];
    int c0 = (int)((i * 8) & 127);
    bf16x8 o;
#pragma unroll
    for (int j = 0; j < 8; ++j) {
      float v = bs2f(y[j]);
      o[j] = f2bs(fmaxf(v * AB[c0 + j] + AB[128 + c0 + j], 0.f));
    }
    X8[i] = o;
  }
}

// ---- BN+ReLU in-place f32 (final output) ----
__global__ __launch_bounds__(256) void bnrelu_f32_k(
    float* __restrict__ Y, const float* __restrict__ AB, long n4) {
  long i = (long)blockIdx.x * 256 + threadIdx.x;
  long stride = (long)gridDim.x * 256;
  for (; i < n4; i += stride) {
    f32x4 y = reinterpret_cast<f32x4*>(Y)[i];
    int c0 = (int)((i * 4) & 127);
    f32x4 A  = *reinterpret_cast<const f32x4*>(AB + c0);
    f32x4 Bv = *reinterpret_cast<const f32x4*>(AB + 128 + c0);
    f32x4 o;
#pragma unroll
    for (int j = 0; j < 4; ++j) o[j] = fmaxf(y[j] * A[j] + Bv[j], 0.f);
    reinterpret_cast<f32x4*>(Y)[i] = o;
  }
}

extern "C" void kernel_launch(void* const* d_in, const int* in_sizes, int n_in,
                              void* d_out, int out_size, void* d_ws, size_t ws_size,
                              hipStream_t stream) {
  const float* unknown = (const float*)d_in[0];
  const float* known   = (const float*)d_in[2];
  const float* uf      = (const float*)d_in[4];
  const float* kf      = (const float*)d_in[5];
  const float* W1      = (const float*)d_in[6];
  const float* g1      = (const float*)d_in[7];
  const float* b1      = (const float*)d_in[8];
  const float* W2      = (const float*)d_in[9];
  const float* g2      = (const float*)d_in[10];
  const float* b2      = (const float*)d_in[11];

  int B    = in_sizes[1];
  int Ntot = in_sizes[0] / 3;
  int Mtot = in_sizes[2] / 3;
  int Ni = Ntot / B, Mi = Mtot / B;

  char* ws = (char*)d_ws;
  size_t off = 0;
  auto alloc = [&](size_t bytes) {
    void* p = ws + off;
    off += (bytes + 255) & ~(size_t)255;
    return p;
  };
  f32x4* k4  = (f32x4*)alloc((size_t)Mtot * 16);
  float* cd  = (float*)alloc((size_t)Ntot * NSLICE * 3 * 4);
  int*   ci  = (int*)  alloc((size_t)Ntot * NSLICE * 3 * 4);
  float* wgt = (float*)alloc((size_t)Ntot * 3 * 4);
  int*   idx = (int*)  alloc((size_t)Ntot * 3 * 4);
  __hip_bfloat16* x0  = (__hip_bfloat16*)alloc((size_t)Ntot * 128 * 2);
  __hip_bfloat16* y1b = (__hip_bfloat16*)alloc((size_t)Ntot * 128 * 2);
  __hip_bfloat16* x1  = (__hip_bfloat16*)alloc((size_t)Ntot * 128 * 2);
  __hip_bfloat16* Wb1 = (__hip_bfloat16*)alloc(128 * 128 * 2);
  __hip_bfloat16* Wb2 = (__hip_bfloat16*)alloc(128 * 128 * 2);
  float* stats = (float*)alloc(2 * 256 * 4);
  float* AB1 = (float*)alloc(256 * 4);
  float* AB2 = (float*)alloc(256 * 4);

  float* y2 = (float*)d_out;
  long n4 = (long)Ntot * 128 / 4;
  long n8 = (long)Ntot * 128 / 8;
  float invN = 1.0f / (float)Ntot;

  hipMemsetAsync(stats, 0, 2 * 256 * 4, stream);
  cvtw_k<<<64, 256, 0, stream>>>(W1, W2, Wb1, Wb2);
  pack_known_k<<<(Mtot + 255) / 256, 256, 0, stream>>>(known, Mtot, k4);
  knn_slice_k<<<(Ntot / 256) * NSLICE, 256, 0, stream>>>(unknown, k4, Ni, Mi, cd, ci);
  knn_merge_k<<<Ntot / 256, 256, 0, stream>>>(unknown, cd, ci, wgt, idx);
  interp_k<<<Ntot / 4, 256, 0, stream>>>(kf, uf, wgt, idx, Ni, Mi, x0);
  gemm_stats_k<<<Ntot / 64, 256, 0, stream>>>(x0, Wb1, nullptr, y1b, stats);
  finalize_k<<<1, 128, 0, stream>>>(stats, g1, b1, invN, AB1);
  bnrelu_bf16_k<<<2048, 256, 0, stream>>>(y1b, AB1, x1, n8);
  gemm_stats_k<<<Ntot / 64, 256, 0, stream>>>(x1, Wb2, y2, nullptr, stats + 256);
  finalize_k<<<1, 128, 0, stream>>>(stats + 256, g2, b2, invN, AB2);
  bnrelu_f32_k<<<2048, 256, 0, stream>>>(y2, AB2, n4);
}

// Round 4
// 219.233 us; speedup vs baseline: 1.4380x; 1.0606x over previous
//
#include <hip/hip_runtime.h>
#include <hip/hip_bf16.h>

#define NSLICE 8

using f32x4  = __attribute__((ext_vector_type(4))) float;
using f32x16 = __attribute__((ext_vector_type(16))) float;
using bf16x8 = __attribute__((ext_vector_type(8))) short;

static __device__ inline short f2bs(float f) {
  __hip_bfloat16 h = __float2bfloat16(f);
  return __builtin_bit_cast(short, h);
}
static __device__ inline float bs2f(short s) {
  return __bfloat162float(__builtin_bit_cast(__hip_bfloat16, s));
}

// ---- prep: convert W1/W2 to bf16 + pack known as (-2x,-2y,-2z,|k|^2) ----
__global__ __launch_bounds__(256) void prep_k(
    const float* __restrict__ W1, const float* __restrict__ W2,
    __hip_bfloat16* __restrict__ Wb1, __hip_bfloat16* __restrict__ Wb2,
    const float* __restrict__ known, int Mtot, f32x4* __restrict__ k4) {
  int i = blockIdx.x * 256 + threadIdx.x;
  if (i < 128 * 128) {
    Wb1[i] = __float2bfloat16(W1[i]);
    Wb2[i] = __float2bfloat16(W2[i]);
  }
  if (i < Mtot) {
    float x = known[(size_t)i * 3 + 0];
    float y = known[(size_t)i * 3 + 1];
    float z = known[(size_t)i * 3 + 2];
    f32x4 v;
    v[0] = -2.f * x; v[1] = -2.f * y; v[2] = -2.f * z;
    v[3] = x * x + y * y + z * z;
    k4[i] = v;
  }
}

// full branchless sorted-insert (3 cmp + 10 sel), strict < keeps earlier/lower idx
#define INSF(dv, mv)                                   \
  {                                                    \
    bool q0 = dv < b0, q1 = dv < b1, q2 = dv < b2;     \
    float P0 = b0, P1 = b1; int Q0 = j0, Q1 = j1;      \
    b2 = q1 ? P1 : (q2 ? dv : b2);                     \
    j2 = q1 ? Q1 : (q2 ? mv : j2);                     \
    b1 = q0 ? P0 : (q1 ? dv : P1);                     \
    j1 = q0 ? Q0 : (q1 ? mv : Q1);                     \
    b0 = q0 ? dv : P0;                                 \
    j0 = q0 ? mv : Q0;                                 \
  }

// ---- 3-NN over a slice: d' = |k|^2 - 2 u.k (monotone in true d^2) ----
__global__ __launch_bounds__(256) void knn_slice_k(
    const float* __restrict__ unknown, const f32x4* __restrict__ k4,
    int Ni, int Mi, float* __restrict__ cd, int* __restrict__ ci) {
  int pb = blockIdx.x / NSLICE;
  int sl = blockIdx.x - pb * NSLICE;
  int p  = pb * 256 + threadIdx.x;
  int b  = (pb * 256) / Ni;               // block-uniform (Ni % 256 == 0)
  const f32x16* kb16 = reinterpret_cast<const f32x16*>(k4 + (size_t)b * Mi);
  int cnt = Mi / NSLICE;
  int m0  = sl * cnt;

  float ux = unknown[(size_t)p * 3 + 0];
  float uy = unknown[(size_t)p * 3 + 1];
  float uz = unknown[(size_t)p * 3 + 2];

  float b0 = 3e38f, b1 = 3e38f, b2 = 3e38f;
  int   j0 = 0,     j1 = 0,     j2 = 0;
#pragma unroll 2
  for (int t = 0; t < cnt; t += 4) {
    f32x16 kc = kb16[(m0 + t) >> 2];      // uniform -> s_load_dwordx16
    float d0 = __fmaf_rn(ux, kc[0],  __fmaf_rn(uy, kc[1],  __fmaf_rn(uz, kc[2],  kc[3])));
    float d1 = __fmaf_rn(ux, kc[4],  __fmaf_rn(uy, kc[5],  __fmaf_rn(uz, kc[6],  kc[7])));
    float d2 = __fmaf_rn(ux, kc[8],  __fmaf_rn(uy, kc[9],  __fmaf_rn(uz, kc[10], kc[11])));
    float d3 = __fmaf_rn(ux, kc[12], __fmaf_rn(uy, kc[13], __fmaf_rn(uz, kc[14], kc[15])));
    float m01 = fminf(d0, d1), m23 = fminf(d2, d3);
    float mn  = fminf(m01, m23);
    if (mn < b2) {                         // per-lane mask; skipped only if no lane qualifies
      float M01 = fmaxf(d0, d1), M23 = fmaxf(d2, d3);
      float snd = fminf(fmaxf(m01, m23), fminf(M01, M23));
      int mi = (d0 == mn) ? 0 : ((d1 == mn) ? 1 : ((d2 == mn) ? 2 : 3));
      int m  = m0 + t + mi;
      // insert mn (mn < b2 holds for active lanes)
      bool c0 = mn < b0, c1 = mn < b1;
      float P0 = b0, P1 = b1; int Q0 = j0, Q1 = j1;
      b2 = c1 ? P1 : mn;             j2 = c1 ? Q1 : m;
      b1 = c0 ? P0 : (c1 ? mn : P1); j1 = c0 ? Q0 : (c1 ? m : Q1);
      b0 = c0 ? mn : P0;             j0 = c0 ? m : Q0;
      if (snd < b2) {                // >=2 qualifiers in this group (rare)
        float e0 = (mi == 0) ? 3e38f : d0;
        float e1 = (mi == 1) ? 3e38f : d1;
        float e2 = (mi == 2) ? 3e38f : d2;
        float e3 = (mi == 3) ? 3e38f : d3;
        INSF(e0, m0 + t + 0);
        INSF(e1, m0 + t + 1);
        INSF(e2, m0 + t + 2);
        INSF(e3, m0 + t + 3);
      }
    }
  }
  size_t o = ((size_t)p * NSLICE + sl) * 3;
  cd[o + 0] = b0; cd[o + 1] = b1; cd[o + 2] = b2;
  ci[o + 0] = j0; ci[o + 1] = j1; ci[o + 2] = j2;
}

// ---- merge per-slice candidates -> weights + idx ----
__global__ __launch_bounds__(256) void knn_merge_k(
    const float* __restrict__ unknown,
    const float* __restrict__ cd, const int* __restrict__ ci,
    float* __restrict__ w, int* __restrict__ idx) {
  int p = blockIdx.x * 256 + threadIdx.x;
  float b0 = 3e38f, b1 = 3e38f, b2 = 3e38f;
  int   j0 = 0,     j1 = 0,     j2 = 0;
  size_t base = (size_t)p * NSLICE * 3;
#pragma unroll
  for (int s = 0; s < NSLICE * 3; ++s) {
    float dv = cd[base + s];
    int   jv = ci[base + s];
    INSF(dv, jv);
  }
  float ux = unknown[(size_t)p * 3 + 0];
  float uy = unknown[(size_t)p * 3 + 1];
  float uz = unknown[(size_t)p * 3 + 2];
  float uu = ux * ux + uy * uy + uz * uz;
  float d0 = sqrtf(fmaxf(b0 + uu, 0.f));
  float d1 = sqrtf(fmaxf(b1 + uu, 0.f));
  float d2 = sqrtf(fmaxf(b2 + uu, 0.f));
  float r0 = 1.f / (d0 + 1e-8f);
  float r1 = 1.f / (d1 + 1e-8f);
  float r2 = 1.f / (d2 + 1e-8f);
  float rs = 1.f / (r0 + r1 + r2);
  size_t o = (size_t)p * 3;
  w[o] = r0 * rs; w[o + 1] = r1 * rs; w[o + 2] = r2 * rs;
  idx[o] = j0; idx[o + 1] = j1; idx[o + 2] = j2;
}

// ---- interpolate + concat -> x0 (bf16, Ntot x 128) ----
__global__ __launch_bounds__(256) void interp_k(
    const float* __restrict__ kf, const float* __restrict__ uf,
    const float* __restrict__ w, const int* __restrict__ idx,
    int Ni, int Mi, __hip_bfloat16* __restrict__ x0) {
  int p    = blockIdx.x * 4 + (threadIdx.x >> 6);  // one wave per point
  int lane = threadIdx.x & 63;
  int b = p / Ni;
  const float* kfb = kf + (size_t)b * Mi * 64;
  size_t o = (size_t)p * 3;
  float w0 = w[o], w1 = w[o + 1], w2 = w[o + 2];
  int   i0 = idx[o], i1 = idx[o + 1], i2 = idx[o + 2];
  float v = w0 * kfb[(size_t)i0 * 64 + lane]
          + w1 * kfb[(size_t)i1 * 64 + lane]
          + w2 * kfb[(size_t)i2 * 64 + lane];
  x0[(size_t)p * 128 + lane]      = __float2bfloat16(v);
  x0[(size_t)p * 128 + 64 + lane] = __float2bfloat16(uf[(size_t)p * 64 + lane]);
}

// ---- layer1: Y = X @ W1^T -> bf16, fused column stats ----
__global__ __launch_bounds__(256) void gemm1_stats_k(
    const __hip_bfloat16* __restrict__ X, const __hip_bfloat16* __restrict__ Wb,
    __hip_bfloat16* __restrict__ Yb, float* __restrict__ stats) {
  __shared__ float ls[128], lq[128];
  if (threadIdx.x < 128) { ls[threadIdx.x] = 0.f; lq[threadIdx.x] = 0.f; }
  __syncthreads();

  int wv   = (blockIdx.x * 256 + threadIdx.x) >> 6;
  int lane = threadIdx.x & 63;
  int row0 = wv * 16;
  int r = lane & 15, g = lane >> 4;
  const short* Xs = reinterpret_cast<const short*>(X);
  const short* Ws = reinterpret_cast<const short*>(Wb);

  bf16x8 a[4];
  size_t abase = (size_t)(row0 + r) * 128 + g * 8;
#pragma unroll
  for (int q = 0; q < 4; ++q)
    a[q] = *reinterpret_cast<const bf16x8*>(Xs + abase + q * 32);

  int rr = row0 + g * 4;
#pragma unroll
  for (int ct = 0; ct < 8; ++ct) {
    f32x4 acc = {0.f, 0.f, 0.f, 0.f};
    size_t bbase = (size_t)(ct * 16 + r) * 128 + g * 8;
#pragma unroll
    for (int q = 0; q < 4; ++q) {
      bf16x8 bfr = *reinterpret_cast<const bf16x8*>(Ws + bbase + q * 32);
      acc = __builtin_amdgcn_mfma_f32_16x16x32_bf16(a[q], bfr, acc, 0, 0, 0);
    }
    int c = ct * 16 + r;
#pragma unroll
    for (int i = 0; i < 4; ++i)
      Yb[(size_t)(rr + i) * 128 + c] = __float2bfloat16(acc[i]);
    float s  = acc[0] + acc[1] + acc[2] + acc[3];
    float q2 = acc[0] * acc[0] + acc[1] * acc[1] + acc[2] * acc[2] + acc[3] * acc[3];
    s  += __shfl_xor(s, 16);  s  += __shfl_xor(s, 32);
    q2 += __shfl_xor(q2, 16); q2 += __shfl_xor(q2, 32);
    if (g == 0) {
      atomicAdd(&ls[c], s);
      atomicAdd(&lq[c], q2);
    }
  }
  __syncthreads();
  if (threadIdx.x < 128) {
    atomicAdd(&stats[threadIdx.x], ls[threadIdx.x]);
    atomicAdd(&stats[128 + threadIdx.x], lq[threadIdx.x]);
  }
}

// ---- layer2: BN1+ReLU applied to A-fragments on load, GEMM, f32 out, stats ----
__global__ __launch_bounds__(256) void gemm2_bn_stats_k(
    const __hip_bfloat16* __restrict__ Y1, const float* __restrict__ AB,
    const __hip_bfloat16* __restrict__ Wb, float* __restrict__ Yf,
    float* __restrict__ stats) {
  __shared__ float ls[128], lq[128];
  if (threadIdx.x < 128) { ls[threadIdx.x] = 0.f; lq[threadIdx.x] = 0.f; }
  __syncthreads();

  int wv   = (blockIdx.x * 256 + threadIdx.x) >> 6;
  int lane = threadIdx.x & 63;
  int row0 = wv * 16;
  int r = lane & 15, g = lane >> 4;
  const short* Ys = reinterpret_cast<const short*>(Y1);
  const short* Ws = reinterpret_cast<const short*>(Wb);

  bf16x8 a[4];
  size_t abase = (size_t)(row0 + r) * 128 + g * 8;
#pragma unroll
  for (int q = 0; q < 4; ++q) {
    bf16x8 raw = *reinterpret_cast<const bf16x8*>(Ys + abase + q * 32);
    int c0 = g * 8 + q * 32;
#pragma unroll
    for (int j = 0; j < 8; ++j) {
      float v = bs2f(raw[j]);
      v = fmaxf(v * AB[c0 + j] + AB[128 + c0 + j], 0.f);
      a[q][j] = f2bs(v);
    }
  }

  int rr = row0 + g * 4;
#pragma unroll
  for (int ct = 0; ct < 8; ++ct) {
    f32x4 acc = {0.f, 0.f, 0.f, 0.f};
    size_t bbase = (size_t)(ct * 16 + r) * 128 + g * 8;
#pragma unroll
    for (int q = 0; q < 4; ++q) {
      bf16x8 bfr = *reinterpret_cast<const bf16x8*>(Ws + bbase + q * 32);
      acc = __builtin_amdgcn_mfma_f32_16x16x32_bf16(a[q], bfr, acc, 0, 0, 0);
    }
    int c = ct * 16 + r;
#pragma unroll
    for (int i = 0; i < 4; ++i)
      Yf[(size_t)(rr + i) * 128 + c] = acc[i];
    float s  = acc[0] + acc[1] + acc[2] + acc[3];
    float q2 = acc[0] * acc[0] + acc[1] * acc[1] + acc[2] * acc[2] + acc[3] * acc[3];
    s  += __shfl_xor(s, 16);  s  += __shfl_xor(s, 32);
    q2 += __shfl_xor(q2, 16); q2 += __shfl_xor(q2, 32);
    if (g == 0) {
      atomicAdd(&ls[c], s);
      atomicAdd(&lq[c], q2);
    }
  }
  __syncthreads();
  if (threadIdx.x < 128) {
    atomicAdd(&stats[threadIdx.x], ls[threadIdx.x]);
    atomicAdd(&stats[128 + threadIdx.x], lq[threadIdx.x]);
  }
}

// ---- stats -> affine coeffs A,B per column ----
__global__ void finalize_k(const float* __restrict__ stats, const float* __restrict__ g,
                           const float* __restrict__ bb, float invN, float* __restrict__ AB) {
  int c = threadIdx.x;
  float mu  = stats[c] * invN;
  float var = stats[128 + c] * invN - mu * mu;
  float A = rsqrtf(var + 1e-5f) * g[c];
  AB[c] = A;
  AB[128 + c] = bb[c] - mu * A;
}

// ---- BN+ReLU in-place f32 (final output) ----
__global__ __launch_bounds__(256) void bnrelu_f32_k(
    float* __restrict__ Y, const float* __restrict__ AB, long n4) {
  long i = (long)blockIdx.x * 256 + threadIdx.x;
  long stride = (long)gridDim.x * 256;
  for (; i < n4; i += stride) {
    f32x4 y = reinterpret_cast<f32x4*>(Y)[i];
    int c0 = (int)((i * 4) & 127);
    f32x4 A  = *reinterpret_cast<const f32x4*>(AB + c0);
    f32x4 Bv = *reinterpret_cast<const f32x4*>(AB + 128 + c0);
    f32x4 o;
#pragma unroll
    for (int j = 0; j < 4; ++j) o[j] = fmaxf(y[j] * A[j] + Bv[j], 0.f);
    reinterpret_cast<f32x4*>(Y)[i] = o;
  }
}

extern "C" void kernel_launch(void* const* d_in, const int* in_sizes, int n_in,
                              void* d_out, int out_size, void* d_ws, size_t ws_size,
                              hipStream_t stream) {
  const float* unknown = (const float*)d_in[0];
  const float* known   = (const float*)d_in[2];
  const float* uf      = (const float*)d_in[4];
  const float* kf      = (const float*)d_in[5];
  const float* W1      = (const float*)d_in[6];
  const float* g1      = (const float*)d_in[7];
  const float* b1      = (const float*)d_in[8];
  const float* W2      = (const float*)d_in[9];
  const float* g2      = (const float*)d_in[10];
  const float* b2      = (const float*)d_in[11];

  int B    = in_sizes[1];
  int Ntot = in_sizes[0] / 3;
  int Mtot = in_sizes[2] / 3;
  int Ni = Ntot / B, Mi = Mtot / B;

  char* ws = (char*)d_ws;
  size_t off = 0;
  auto alloc = [&](size_t bytes) {
    void* p = ws + off;
    off += (bytes + 255) & ~(size_t)255;
    return p;
  };
  f32x4* k4  = (f32x4*)alloc((size_t)Mtot * 16);
  float* cd  = (float*)alloc((size_t)Ntot * NSLICE * 3 * 4);
  int*   ci  = (int*)  alloc((size_t)Ntot * NSLICE * 3 * 4);
  float* wgt = (float*)alloc((size_t)Ntot * 3 * 4);
  int*   idx = (int*)  alloc((size_t)Ntot * 3 * 4);
  __hip_bfloat16* x0  = (__hip_bfloat16*)alloc((size_t)Ntot * 128 * 2);
  __hip_bfloat16* y1b = (__hip_bfloat16*)alloc((size_t)Ntot * 128 * 2);
  __hip_bfloat16* Wb1 = (__hip_bfloat16*)alloc(128 * 128 * 2);
  __hip_bfloat16* Wb2 = (__hip_bfloat16*)alloc(128 * 128 * 2);
  float* stats = (float*)alloc(2 * 256 * 4);
  float* AB1 = (float*)alloc(256 * 4);
  float* AB2 = (float*)alloc(256 * 4);

  float* y2 = (float*)d_out;
  long n4 = (long)Ntot * 128 / 4;
  float invN = 1.0f / (float)Ntot;

  hipMemsetAsync(stats, 0, 2 * 256 * 4, stream);
  prep_k<<<(128 * 128 + 255) / 256, 256, 0, stream>>>(W1, W2, Wb1, Wb2, known, Mtot, k4);
  knn_slice_k<<<(Ntot / 256) * NSLICE, 256, 0, stream>>>(unknown, k4, Ni, Mi, cd, ci);
  knn_merge_k<<<Ntot / 256, 256, 0, stream>>>(unknown, cd, ci, wgt, idx);
  interp_k<<<Ntot / 4, 256, 0, stream>>>(kf, uf, wgt, idx, Ni, Mi, x0);
  gemm1_stats_k<<<Ntot / 64, 256, 0, stream>>>(x0, Wb1, y1b, stats);
  finalize_k<<<1, 128, 0, stream>>>(stats, g1, b1, invN, AB1);
  gemm2_bn_stats_k<<<Ntot / 64, 256, 0, stream>>>(y1b, AB1, Wb2, y2, stats + 256);
  finalize_k<<<1, 128, 0, stream>>>(stats + 256, g2, b2, invN, AB2);
  bnrelu_f32_k<<<2048, 256, 0, stream>>>(y2, AB2, n4);
}